// Round 5
// baseline (429.177 us; speedup 1.0000x reference)
//
#include <hip/hip_runtime.h>
#include <hip/hip_bf16.h>
#include <math.h>

// Problem constants
#define BATCH 16
#define L1 32
#define L2 128
#define DEC 512
#define MEM 512
#define TOPN 50
#define NROWS (BATCH * L1 * L2)   // 65536 word rows
#define NBQ (BATCH * L1)          // 512 (b,q) rows

typedef short short8 __attribute__((ext_vector_type(8)));
typedef float f32x16 __attribute__((ext_vector_type(16)));

// ---------------- ws layout (floats) ----------------
#define WS_WP     0          // perm bf16 Wm : 32768 slots x 16B = floats [0,131072)
#define WS_WP2    131072     // (unused now)
#define WS_BIAS1  262144
#define WS_BIAS2  270336
#define WS_DOCSC  278528     // doc scores [512] -> end 279040 (~1.07 MB total)

// packed pair via v_cvt_pk_bf16_f32
__device__ __forceinline__ unsigned int pkbf(float a, float b) {
    __hip_bfloat162 h = __float22bfloat162_rn(float2{a, b});
    union { __hip_bfloat162 h; unsigned int u; } c{h};
    return c.u;
}

__device__ __forceinline__ float fast_tanh(float x) {
    return 1.f - 2.f / (__expf(2.f * x) + 1.f);
}

__device__ __forceinline__ float wave_sum64(float v) {
    v += __shfl_xor(v, 1);
    v += __shfl_xor(v, 2);
    v += __shfl_xor(v, 4);
    v += __shfl_xor(v, 8);
    v += __shfl_xor(v, 16);
    v += __shfl_xor(v, 32);
    return v;
}

// ============ kernel 0 (setup): permute Wm + bias via wave-per-output + zero ctx ============
// permute slot s (16B) holds Wm[d][k..k+7] bf16: s = C*1024 + nt*64 + k8*32 + n
//   d = nt*32+n ; k = C*16 + k8*8      (layout HW-verified)
__global__ __launch_bounds__(256) void setup_kernel(
    const float* __restrict__ Wm,
    unsigned short* __restrict__ Wp,
    const float* __restrict__ dec, const float* __restrict__ topic,
    const float* __restrict__ Wd, const float* __restrict__ Wt,
    const float* __restrict__ Wd2, const float* __restrict__ Wt2,
    float* __restrict__ bias1, float* __restrict__ bias2,
    float* __restrict__ ctx_out)
{
    const int bid = blockIdx.x;
    const int tid = threadIdx.x;
    if (bid < 128) {
        int s = bid * 256 + tid;                    // 0..32767
        int C = s >> 10;
        int u = s & 1023;
        int nt = u >> 6, k8 = (u >> 5) & 1, n_in = u & 31;
        int d = nt * 32 + n_in;
        int k = C * 16 + k8 * 8;

        const float4* src = (const float4*)(Wm + (size_t)d * DEC + k);
        float4 v0 = src[0], v1 = src[1];
        uint4 v;
        v.x = pkbf(v0.x, v0.y); v.y = pkbf(v0.z, v0.w);
        v.z = pkbf(v1.x, v1.y); v.w = pkbf(v1.z, v1.w);
        ((uint4*)Wp)[s] = v;
    } else if (bid < 128 + 4096) {
        // one bias output per wave: gw in [0,16384)
        int gw = (bid - 128) * 4 + (tid >> 6);
        int lane = tid & 63;
        int mat = gw >> 13;                 // 0: bias1 (Wd,Wt), 1: bias2 (Wd2,Wt2)
        int rem = gw & 8191;
        int bb = rem >> 9;                  // 0..15
        int d = rem & 511;                  // 0..511

        const float* wrow = (mat ? Wd2 : Wd) + (size_t)d * DEC;
        const float* drow = dec + (size_t)bb * DEC;
        float4 a0 = ((const float4*)wrow)[lane * 2];
        float4 a1 = ((const float4*)wrow)[lane * 2 + 1];
        float4 x0 = ((const float4*)drow)[lane * 2];
        float4 x1 = ((const float4*)drow)[lane * 2 + 1];
        float acc = a0.x * x0.x;
        acc = fmaf(a0.y, x0.y, acc);
        acc = fmaf(a0.z, x0.z, acc);
        acc = fmaf(a0.w, x0.w, acc);
        acc = fmaf(a1.x, x1.x, acc);
        acc = fmaf(a1.y, x1.y, acc);
        acc = fmaf(a1.z, x1.z, acc);
        acc = fmaf(a1.w, x1.w, acc);
        const float* trow = (mat ? Wt2 : Wt) + (size_t)d * TOPN;
        if (lane < TOPN) acc = fmaf(trow[lane], topic[bb * TOPN + lane], acc);
#pragma unroll
        for (int o = 1; o <= 32; o <<= 1) acc += __shfl_xor(acc, o);
        if (lane == 0) (mat ? bias2 : bias1)[bb * DEC + d] = acc;
    } else {
        // zero ctx accumulator region of d_out (8192 floats), 4 blocks
        int i = (bid - (128 + 4096)) * 256 + tid;   // 0..1023
        float4 z = {0.f, 0.f, 0.f, 0.f};
        ((float4*)ctx_out)[i * 2] = z;
        ((float4*)ctx_out)[i * 2 + 1] = z;
    }
}

// ============ doc score kernel: wide fp32 VALU (256 blocks, 512 thr) ============
// Block = 2 doc rows (same batch). Doc row held in registers (8 floats/lane).
// Wave w computes d = w*64..+63, 2 d per iter; weights read lane-sliced (coalesced,
// L2-resident after first blocks). Full 64-lane shuffle reduce per dot.
// Replaces the 4-block MFMA doc dispatch that took 117 us on 4 CUs.
__global__ __launch_bounds__(512) void doc_score_kernel(
    const float* __restrict__ Xd,     // doc_memory [512][512]
    const float* __restrict__ Wm2,    // [512][512] row-major [d][m]
    const float* __restrict__ Wv2,    // [512]
    const float* __restrict__ bias2,  // [16][512]
    float* __restrict__ doc_scores)   // [512]
{
    __shared__ float wsum[2][8];
    const int tid = threadIdx.x;
    const int lane = tid & 63;
    const int w = tid >> 6;            // 0..7
    const int row0 = blockIdx.x * 2;   // even -> both rows same batch
    const int b = row0 >> 5;

    const float4* X0 = (const float4*)(Xd + (size_t)row0 * MEM) + lane * 2;
    const float4* X1 = (const float4*)(Xd + (size_t)(row0 + 1) * MEM) + lane * 2;
    float4 xa0 = X0[0], xb0 = X0[1];
    float4 xa1 = X1[0], xb1 = X1[1];

    float s0 = 0.f, s1 = 0.f;
#pragma unroll 2
    for (int dd = 0; dd < 64; dd += 2) {
        const int d = w * 64 + dd;
        const float4* W0 = (const float4*)(Wm2 + (size_t)d * MEM) + lane * 2;
        const float4* W1 = (const float4*)(Wm2 + (size_t)(d + 1) * MEM) + lane * 2;
        float4 wa0 = W0[0], wb0 = W0[1];
        float4 wa1 = W1[0], wb1 = W1[1];

        float p00 = wa0.x * xa0.x, p01 = wa1.x * xa0.x;
        float p10 = wa0.x * xa1.x, p11 = wa1.x * xa1.x;
        p00 = fmaf(wa0.y, xa0.y, p00); p01 = fmaf(wa1.y, xa0.y, p01);
        p10 = fmaf(wa0.y, xa1.y, p10); p11 = fmaf(wa1.y, xa1.y, p11);
        p00 = fmaf(wa0.z, xa0.z, p00); p01 = fmaf(wa1.z, xa0.z, p01);
        p10 = fmaf(wa0.z, xa1.z, p10); p11 = fmaf(wa1.z, xa1.z, p11);
        p00 = fmaf(wa0.w, xa0.w, p00); p01 = fmaf(wa1.w, xa0.w, p01);
        p10 = fmaf(wa0.w, xa1.w, p10); p11 = fmaf(wa1.w, xa1.w, p11);
        p00 = fmaf(wb0.x, xb0.x, p00); p01 = fmaf(wb1.x, xb0.x, p01);
        p10 = fmaf(wb0.x, xb1.x, p10); p11 = fmaf(wb1.x, xb1.x, p11);
        p00 = fmaf(wb0.y, xb0.y, p00); p01 = fmaf(wb1.y, xb0.y, p01);
        p10 = fmaf(wb0.y, xb1.y, p10); p11 = fmaf(wb1.y, xb1.y, p11);
        p00 = fmaf(wb0.z, xb0.z, p00); p01 = fmaf(wb1.z, xb0.z, p01);
        p10 = fmaf(wb0.z, xb1.z, p10); p11 = fmaf(wb1.z, xb1.z, p11);
        p00 = fmaf(wb0.w, xb0.w, p00); p01 = fmaf(wb1.w, xb0.w, p01);
        p10 = fmaf(wb0.w, xb1.w, p10); p11 = fmaf(wb1.w, xb1.w, p11);

        p00 = wave_sum64(p00);
        p01 = wave_sum64(p01);
        p10 = wave_sum64(p10);
        p11 = wave_sum64(p11);
        if (lane == 0) {
            float wva = Wv2[d], wvb = Wv2[d + 1];
            float bsa = bias2[b * DEC + d], bsb = bias2[b * DEC + d + 1];
            s0 += fmaf(wva, fast_tanh(p00 + bsa), wvb * fast_tanh(p01 + bsb));
            s1 += fmaf(wva, fast_tanh(p10 + bsa), wvb * fast_tanh(p11 + bsb));
        }
    }
    if (lane == 0) { wsum[0][w] = s0; wsum[1][w] = s1; }
    __syncthreads();
    if (tid < 2) {
        float s = 0.f;
#pragma unroll
        for (int i = 0; i < 8; ++i) s += wsum[tid][i];
        doc_scores[row0 + tid] = s;
    }
}

// ============ fused word kernel (R8): 16 waves x 32-d, streamed A quarters ============
// Block = one (b,q): 128 rows, 1024 threads = 16 waves; wave w owns d = w*32..+31.
// acc[4] = 64 AGPR; staging sb[4] + B ring rb[4] -> ~120 regs/wave => 16 waves/CU
// (4/SIMD, 2x the occupancy of the acc[8] design whose 248 regs pinned us at 8 waves/CU).
// A is SINGLE-USE: streamed through 2 x 33KB quarter LDS buffers (4 lgkm-only barriers),
// staging loads issued one quarter ahead (quarter compute >> HBM latency).
// B: per-wave 1 uint4/step from L2, 4-deep ring.
__global__ __launch_bounds__(1024) void word_fused_kernel(
    const float* __restrict__ X,            // word_memory [65536][512]
    const unsigned short* __restrict__ Wp_, // permuted bf16 Wm
    const float* __restrict__ Wv_,          // [512]
    const float* __restrict__ bias_,        // [16][512]
    const float* __restrict__ doc_scores,   // [512]
    const int* __restrict__ doc_mask,       // [512]
    const int* __restrict__ word_mask,      // [65536]
    float* __restrict__ rescaled_out,       // d_out + 8192
    float* __restrict__ ctx_out)            // d_out [16][512], pre-zeroed, atomic
{
    __shared__ __align__(16) char lsQ[2][128 * 264];   // 2 x 33792 B quarter buffers
    __shared__ float red[16][128];
    __shared__ float sS[128];
    __shared__ float rmax2[2], rsum2[2];
    __shared__ float s_dattn;
    __shared__ __align__(16) float4 part[7 * 128];

    const int tid = threadIdx.x;
    const int lane = tid & 63;
    const int w = tid >> 6;            // 0..15: 32-d slice
    const int bid = blockIdx.x;
    const int r0 = bid * 128;
    const int col = lane & 31;
    const int h = lane >> 5;

    // ---- staging map: thread covers (row srow0+32i, f4col scol) of each quarter ----
    const int scol = tid & 31;
    const int srow0 = tid >> 5;        // 0..31
    const float4* Xbase = (const float4*)X + (size_t)(r0 + srow0) * 128 + scol;

    float4 sb[4];
#define ISSUEQ(qq) { _Pragma("unroll") for (int i = 0; i < 4; ++i) \
        sb[i] = Xbase[(size_t)(32 * i) * 128 + (qq) * 32]; }
#define WRITEQ(pb) { char* wp = lsQ[pb] + (size_t)srow0 * 264 + scol * 8; \
    _Pragma("unroll") for (int i = 0; i < 4; ++i) { \
        uint2 ww; ww.x = pkbf(sb[i].x, sb[i].y); ww.y = pkbf(sb[i].z, sb[i].w); \
        *(uint2*)(wp + (size_t)(32 * i) * 264) = ww; } }
#define LGKMBAR { asm volatile("s_waitcnt lgkmcnt(0)" ::: "memory"); \
                  __builtin_amdgcn_s_barrier(); asm volatile("" ::: "memory"); }
#define MFMA(a, bb, c) __builtin_amdgcn_mfma_f32_32x32x16_bf16(a, bb, c, 0, 0, 0)

    // ---- B addressing: slot(chunk c, lane) = c*1024 + w*64 + lane ----
    const uint4* Bq4 = (const uint4*)Wp_;
    const int vB = w * 64 + lane;

    f32x16 acc0, acc1, acc2, acc3;
    acc0 = acc1 = acc2 = acc3 =
        (f32x16){0.f,0.f,0.f,0.f, 0.f,0.f,0.f,0.f, 0.f,0.f,0.f,0.f, 0.f,0.f,0.f,0.f};

    uint4 rb[4];

#define STEP(f, pb) { \
        union { uint4 u; short8 s8; } bb{rb[(f) & 3]}; \
        if ((f) + 4 < 32) rb[(f) & 3] = Bq4[(size_t)((f) + 4) * 1024 + vB]; \
        const char* ab = lsQ[pb] + (size_t)col * 264 + h * 16 + ((f) & 7) * 32; \
        short8 a0 = *(const short8*)(ab); \
        short8 a1 = *(const short8*)(ab + 32 * 264); \
        short8 a2 = *(const short8*)(ab + 64 * 264); \
        short8 a3 = *(const short8*)(ab + 96 * 264); \
        acc0 = MFMA(a0, bb.s8, acc0); \
        acc1 = MFMA(a1, bb.s8, acc1); \
        acc2 = MFMA(a2, bb.s8, acc2); \
        acc3 = MFMA(a3, bb.s8, acc3); }

#define QUARTER(f0, pb) { STEP((f0)+0, pb) STEP((f0)+1, pb) STEP((f0)+2, pb) STEP((f0)+3, pb) \
                          STEP((f0)+4, pb) STEP((f0)+5, pb) STEP((f0)+6, pb) STEP((f0)+7, pb) }

    // ---- prologue ----
    ISSUEQ(0);

    // doc softmax for this block's (b,q) — overlaps load latency
    if (tid < 32) {
        int b_ = bid >> 5;
        int di = b_ * 32 + tid;
        float dsv = doc_scores[di];
        if (doc_mask[di] == 0) dsv = -INFINITY;
        float mx = dsv;
#pragma unroll
        for (int o = 1; o <= 16; o <<= 1) mx = fmaxf(mx, __shfl_xor(mx, o));
        float e = __expf(dsv - mx);
        float sum = e;
#pragma unroll
        for (int o = 1; o <= 16; o <<= 1) sum += __shfl_xor(sum, o);
        if (tid == (bid & 31)) s_dattn = e / sum;
    }

    WRITEQ(0);
#pragma unroll
    for (int f = 0; f < 4; ++f) rb[f] = Bq4[(size_t)f * 1024 + vB];
    LGKMBAR;

    ISSUEQ(1);
    QUARTER(0, 0);
    WRITEQ(1);
    LGKMBAR;

    ISSUEQ(2);
    QUARTER(8, 1);
    WRITEQ(0);
    LGKMBAR;

    ISSUEQ(3);
    QUARTER(16, 0);
    WRITEQ(1);
    LGKMBAR;

    QUARTER(24, 1);

    // ---- epilogue: tanh + Wv partial over this wave's 32 d ----
    // C/D layout (32x32, HW-verified): col = lane&31, row_in = (r&3)+8*(r>>2)+4*h
    {
        const int d0 = w * 32 + col;
        const float wv0 = Wv_[d0];
        const int bb_ = bid >> 5;
        const float bs0 = bias_[bb_ * DEC + d0];
#define EPI(rg, accN) { _Pragma("unroll") for (int r = 0; r < 16; ++r) { \
            float val = wv0 * fast_tanh(accN[r] + bs0); \
            val += __shfl_xor(val, 16); val += __shfl_xor(val, 8); \
            val += __shfl_xor(val, 4);  val += __shfl_xor(val, 2); \
            val += __shfl_xor(val, 1); \
            if (col == r) red[w][(rg) * 32 + ((r & 3) + 8 * (r >> 2) + 4 * h)] = val; } }
        EPI(0, acc0) EPI(1, acc1) EPI(2, acc2) EPI(3, acc3)
#undef EPI
    }
    __syncthreads();

    // ---- word softmax over 128 rows (threads 0..127) ----
    float e = 0.f, sv = 0.f;
    if (tid < 128) {
        sv = 0.f;
#pragma unroll
        for (int i = 0; i < 16; ++i) sv += red[i][tid];
        if (word_mask[r0 + tid] == 0) sv = -INFINITY;
        float mx = sv;
#pragma unroll
        for (int o = 1; o <= 32; o <<= 1) mx = fmaxf(mx, __shfl_xor(mx, o));
        if (lane == 0) rmax2[tid >> 6] = mx;
    }
    __syncthreads();
    if (tid < 128) {
        float mx = fmaxf(rmax2[0], rmax2[1]);
        e = __expf(sv - mx);
        float sum = e;
#pragma unroll
        for (int o = 1; o <= 32; o <<= 1) sum += __shfl_xor(sum, o);
        if (lane == 0) rsum2[tid >> 6] = sum;
    }
    __syncthreads();
    if (tid < 128) {
        float sum = rsum2[0] + rsum2[1];
        float resc = s_dattn * (e / sum);
        sS[tid] = resc;
        rescaled_out[r0 + tid] = resc;
    }
    __syncthreads();

    // ---- context partial (fp32 X re-read, L3-hot) + atomic accumulate ----
    const int b_ = bid >> 5;
    const int hh = tid >> 7;          // 0..7: 16-row group
    const int m4 = tid & 127;         // float4 index in m
    const float4* Xr = (const float4*)X + (size_t)(r0 + hh * 16) * 128 + m4;
    float4 a = {0.f, 0.f, 0.f, 0.f};
#pragma unroll 4
    for (int i = 0; i < 16; ++i) {
        float rr = sS[hh * 16 + i];
        float4 v = Xr[(size_t)i * 128];
        a.x = fmaf(rr, v.x, a.x);
        a.y = fmaf(rr, v.y, a.y);
        a.z = fmaf(rr, v.z, a.z);
        a.w = fmaf(rr, v.w, a.w);
    }
    if (hh) part[(hh - 1) * 128 + m4] = a;
    __syncthreads();
    if (hh == 0) {
#pragma unroll
        for (int p = 0; p < 7; ++p) {
            float4 pp = part[p * 128 + m4];
            a.x += pp.x; a.y += pp.y; a.z += pp.z; a.w += pp.w;
        }
        float* dst = ctx_out + (size_t)b_ * MEM + m4 * 4;
        atomicAdd(dst + 0, a.x);
        atomicAdd(dst + 1, a.y);
        atomicAdd(dst + 2, a.z);
        atomicAdd(dst + 3, a.w);
    }
}

extern "C" void kernel_launch(void* const* d_in, const int* in_sizes, int n_in,
                              void* d_out, int out_size, void* d_ws, size_t ws_size,
                              hipStream_t stream) {
    const float* decoder_state = (const float*)d_in[0];
    const float* doc_memory    = (const float*)d_in[1];
    const float* word_memory   = (const float*)d_in[2];
    const float* topic_dist    = (const float*)d_in[3];
    const int*   doc_mask      = (const int*)d_in[4];
    const int*   word_mask     = (const int*)d_in[5];
    const float* Wv  = (const float*)d_in[6];
    const float* Wd  = (const float*)d_in[7];
    const float* Wt  = (const float*)d_in[8];
    const float* Wm  = (const float*)d_in[9];
    const float* Wv2 = (const float*)d_in[10];
    const float* Wd2 = (const float*)d_in[11];
    const float* Wt2 = (const float*)d_in[12];
    const float* Wm2 = (const float*)d_in[13];

    float* ws = (float*)d_ws;
    unsigned short* Wp  = (unsigned short*)(ws + WS_WP);
    float* bias1       = ws + WS_BIAS1;
    float* bias2       = ws + WS_BIAS2;
    float* doc_scores  = ws + WS_DOCSC;

    float* ctx_out      = (float*)d_out;                 // [16][512]
    float* rescaled_out = (float*)d_out + BATCH * MEM;   // [16][32][128]

    setup_kernel<<<128 + 4096 + 4, 256, 0, stream>>>(Wm, Wp,
                                                     decoder_state, topic_dist,
                                                     Wd, Wt, Wd2, Wt2, bias1, bias2, ctx_out);
    doc_score_kernel<<<256, 512, 0, stream>>>(doc_memory, Wm2, Wv2, bias2, doc_scores);
    word_fused_kernel<<<NBQ, 1024, 0, stream>>>(word_memory, Wp, Wv, bias1,
                                                doc_scores, doc_mask, word_mask,
                                                rescaled_out, ctx_out);
}

// Round 6
// 362.852 us; speedup vs baseline: 1.1828x; 1.1828x over previous
//
#include <hip/hip_runtime.h>
#include <hip/hip_bf16.h>
#include <math.h>

// Problem constants
#define BATCH 16
#define L1 32
#define L2 128
#define DEC 512
#define MEM 512
#define TOPN 50
#define NROWS (BATCH * L1 * L2)   // 65536 word rows
#define NBQ (BATCH * L1)          // 512 (b,q) rows

typedef short short8 __attribute__((ext_vector_type(8)));
typedef float f32x16 __attribute__((ext_vector_type(16)));

// ---------------- ws layout (floats) ----------------
#define WS_WP     0          // perm bf16 Wm : 32768 slots x 16B = floats [0,131072)
#define WS_BIAS1  262144
#define WS_BIAS2  270336
#define WS_DOCSC  278528     // doc scores [512]

// packed pair via v_cvt_pk_bf16_f32
__device__ __forceinline__ unsigned int pkbf(float a, float b) {
    __hip_bfloat162 h = __float22bfloat162_rn(float2{a, b});
    union { __hip_bfloat162 h; unsigned int u; } c{h};
    return c.u;
}

__device__ __forceinline__ float fast_tanh(float x) {
    return 1.f - 2.f / (__expf(2.f * x) + 1.f);
}

__device__ __forceinline__ float wave_sum64(float v) {
    v += __shfl_xor(v, 1);
    v += __shfl_xor(v, 2);
    v += __shfl_xor(v, 4);
    v += __shfl_xor(v, 8);
    v += __shfl_xor(v, 16);
    v += __shfl_xor(v, 32);
    return v;
}

// ============ kernel 0 (setup): permute Wm + bias via wave-per-output + zero ctx ============
// permute slot s (16B) holds Wm[d][k..k+7] bf16: s = C*1024 + nt*64 + k8*32 + n
//   d = nt*32+n ; k = C*16 + k8*8      (layout HW-verified)
__global__ __launch_bounds__(256) void setup_kernel(
    const float* __restrict__ Wm,
    unsigned short* __restrict__ Wp,
    const float* __restrict__ dec, const float* __restrict__ topic,
    const float* __restrict__ Wd, const float* __restrict__ Wt,
    const float* __restrict__ Wd2, const float* __restrict__ Wt2,
    float* __restrict__ bias1, float* __restrict__ bias2,
    float* __restrict__ ctx_out)
{
    const int bid = blockIdx.x;
    const int tid = threadIdx.x;
    if (bid < 128) {
        int s = bid * 256 + tid;                    // 0..32767
        int C = s >> 10;
        int u = s & 1023;
        int nt = u >> 6, k8 = (u >> 5) & 1, n_in = u & 31;
        int d = nt * 32 + n_in;
        int k = C * 16 + k8 * 8;

        const float4* src = (const float4*)(Wm + (size_t)d * DEC + k);
        float4 v0 = src[0], v1 = src[1];
        uint4 v;
        v.x = pkbf(v0.x, v0.y); v.y = pkbf(v0.z, v0.w);
        v.z = pkbf(v1.x, v1.y); v.w = pkbf(v1.z, v1.w);
        ((uint4*)Wp)[s] = v;
    } else if (bid < 128 + 4096) {
        // one bias output per wave: gw in [0,16384)
        int gw = (bid - 128) * 4 + (tid >> 6);
        int lane = tid & 63;
        int mat = gw >> 13;                 // 0: bias1 (Wd,Wt), 1: bias2 (Wd2,Wt2)
        int rem = gw & 8191;
        int bb = rem >> 9;                  // 0..15
        int d = rem & 511;                  // 0..511

        const float* wrow = (mat ? Wd2 : Wd) + (size_t)d * DEC;
        const float* drow = dec + (size_t)bb * DEC;
        float4 a0 = ((const float4*)wrow)[lane * 2];
        float4 a1 = ((const float4*)wrow)[lane * 2 + 1];
        float4 x0 = ((const float4*)drow)[lane * 2];
        float4 x1 = ((const float4*)drow)[lane * 2 + 1];
        float acc = a0.x * x0.x;
        acc = fmaf(a0.y, x0.y, acc);
        acc = fmaf(a0.z, x0.z, acc);
        acc = fmaf(a0.w, x0.w, acc);
        acc = fmaf(a1.x, x1.x, acc);
        acc = fmaf(a1.y, x1.y, acc);
        acc = fmaf(a1.z, x1.z, acc);
        acc = fmaf(a1.w, x1.w, acc);
        const float* trow = (mat ? Wt2 : Wt) + (size_t)d * TOPN;
        if (lane < TOPN) acc = fmaf(trow[lane], topic[bb * TOPN + lane], acc);
#pragma unroll
        for (int o = 1; o <= 32; o <<= 1) acc += __shfl_xor(acc, o);
        if (lane == 0) (mat ? bias2 : bias1)[bb * DEC + d] = acc;
    } else {
        // zero ctx accumulator region of d_out (8192 floats), 4 blocks
        int i = (bid - (128 + 4096)) * 256 + tid;   // 0..1023
        float4 z = {0.f, 0.f, 0.f, 0.f};
        ((float4*)ctx_out)[i * 2] = z;
        ((float4*)ctx_out)[i * 2 + 1] = z;
    }
}

// ============ doc score kernel: wide fp32 VALU (256 blocks, 512 thr) ============
// Block = 2 doc rows (same batch). Replaces the 4-block MFMA doc dispatch (117 us on 4 CUs).
__global__ __launch_bounds__(512) void doc_score_kernel(
    const float* __restrict__ Xd,     // doc_memory [512][512]
    const float* __restrict__ Wm2,    // [512][512] row-major [d][m]
    const float* __restrict__ Wv2,    // [512]
    const float* __restrict__ bias2,  // [16][512]
    float* __restrict__ doc_scores)   // [512]
{
    __shared__ float wsum[2][8];
    const int tid = threadIdx.x;
    const int lane = tid & 63;
    const int w = tid >> 6;            // 0..7
    const int row0 = blockIdx.x * 2;   // even -> both rows same batch
    const int b = row0 >> 5;

    const float4* X0 = (const float4*)(Xd + (size_t)row0 * MEM) + lane * 2;
    const float4* X1 = (const float4*)(Xd + (size_t)(row0 + 1) * MEM) + lane * 2;
    float4 xa0 = X0[0], xb0 = X0[1];
    float4 xa1 = X1[0], xb1 = X1[1];

    float s0 = 0.f, s1 = 0.f;
#pragma unroll 2
    for (int dd = 0; dd < 64; dd += 2) {
        const int d = w * 64 + dd;
        const float4* W0 = (const float4*)(Wm2 + (size_t)d * MEM) + lane * 2;
        const float4* W1 = (const float4*)(Wm2 + (size_t)(d + 1) * MEM) + lane * 2;
        float4 wa0 = W0[0], wb0 = W0[1];
        float4 wa1 = W1[0], wb1 = W1[1];

        float p00 = wa0.x * xa0.x, p01 = wa1.x * xa0.x;
        float p10 = wa0.x * xa1.x, p11 = wa1.x * xa1.x;
        p00 = fmaf(wa0.y, xa0.y, p00); p01 = fmaf(wa1.y, xa0.y, p01);
        p10 = fmaf(wa0.y, xa1.y, p10); p11 = fmaf(wa1.y, xa1.y, p11);
        p00 = fmaf(wa0.z, xa0.z, p00); p01 = fmaf(wa1.z, xa0.z, p01);
        p10 = fmaf(wa0.z, xa1.z, p10); p11 = fmaf(wa1.z, xa1.z, p11);
        p00 = fmaf(wa0.w, xa0.w, p00); p01 = fmaf(wa1.w, xa0.w, p01);
        p10 = fmaf(wa0.w, xa1.w, p10); p11 = fmaf(wa1.w, xa1.w, p11);
        p00 = fmaf(wb0.x, xb0.x, p00); p01 = fmaf(wb1.x, xb0.x, p01);
        p10 = fmaf(wb0.x, xb1.x, p10); p11 = fmaf(wb1.x, xb1.x, p11);
        p00 = fmaf(wb0.y, xb0.y, p00); p01 = fmaf(wb1.y, xb0.y, p01);
        p10 = fmaf(wb0.y, xb1.y, p10); p11 = fmaf(wb1.y, xb1.y, p11);
        p00 = fmaf(wb0.z, xb0.z, p00); p01 = fmaf(wb1.z, xb0.z, p01);
        p10 = fmaf(wb0.z, xb1.z, p10); p11 = fmaf(wb1.z, xb1.z, p11);
        p00 = fmaf(wb0.w, xb0.w, p00); p01 = fmaf(wb1.w, xb0.w, p01);
        p10 = fmaf(wb0.w, xb1.w, p10); p11 = fmaf(wb1.w, xb1.w, p11);

        p00 = wave_sum64(p00);
        p01 = wave_sum64(p01);
        p10 = wave_sum64(p10);
        p11 = wave_sum64(p11);
        if (lane == 0) {
            float wva = Wv2[d], wvb = Wv2[d + 1];
            float bsa = bias2[b * DEC + d], bsb = bias2[b * DEC + d + 1];
            s0 += fmaf(wva, fast_tanh(p00 + bsa), wvb * fast_tanh(p01 + bsb));
            s1 += fmaf(wva, fast_tanh(p10 + bsa), wvb * fast_tanh(p11 + bsb));
        }
    }
    if (lane == 0) { wsum[0][w] = s0; wsum[1][w] = s1; }
    __syncthreads();
    if (tid < 2) {
        float s = 0.f;
#pragma unroll
        for (int i = 0; i < 8; ++i) s += wsum[tid][i];
        doc_scores[row0 + tid] = s;
    }
}

// ============ persistent word kernel (R9): 256 blocks x 2 tiles, overlapped ============
// Block = 2 (b,q) tiles (bid, bid+256), 512 threads = 8 waves, acc[8] = 128 AGPR.
// A streamed via 4 LDS quarter slots (33 KB each); tile2's staging issued during
// tile1's later quarters and tail, so the HBM stream never stalls on the tail.
// lgkm-only phase barriers; B from L2 via 4-deep register ring (reloaded at tile seam).
// Peak regs ~222 (1 sb buffer in flight during tail) -> no spill (watch WRITE_SIZE).
__global__ __launch_bounds__(512, 2) void word_fused_kernel(
    const float* __restrict__ X,            // word_memory [65536][512]
    const unsigned short* __restrict__ Wp_, // permuted bf16 Wm
    const float* __restrict__ Wv_,          // [512]
    const float* __restrict__ bias_,        // [16][512]
    const float* __restrict__ doc_scores,   // [512]
    const int* __restrict__ doc_mask,       // [512]
    const int* __restrict__ word_mask,      // [65536]
    float* __restrict__ rescaled_out,       // d_out + 8192
    float* __restrict__ ctx_out)            // d_out [16][512], pre-zeroed, atomic
{
    __shared__ __align__(16) char lsQ[4][128 * 264];   // 4 x 33792 B quarter slots
    __shared__ float red[8][128];
    __shared__ float sS[128];
    __shared__ float rmax2[2], rsum2[2];
    __shared__ float s_dattn2[2];
    __shared__ __align__(16) float4 part[3 * 128];

    const int tid = threadIdx.x;
    const int lane = tid & 63;
    const int w = tid >> 6;            // 0..7: 64-d slice
    const int bid = blockIdx.x;        // 0..255
    const int col = lane & 31;
    const int h = lane >> 5;

    const int bq1 = bid, bq2 = bid + 256;
    const int r01 = bq1 * 128, r02 = bq2 * 128;
    const int b1 = bq1 >> 5, b2 = bq2 >> 5;

    // ---- staging map: thread covers (rows srow0+16i, f4col scol) of a quarter ----
    const int scol = tid & 31;
    const int srow0 = tid >> 5;        // 0..15
    const float4* Xb1 = (const float4*)X + (size_t)(r01 + srow0) * 128 + scol;
    const float4* Xb2 = (const float4*)X + (size_t)(r02 + srow0) * 128 + scol;

#define ISSUEQ(buf, qq, Xb) { _Pragma("unroll") for (int i = 0; i < 8; ++i) \
        buf[i] = (Xb)[(size_t)(16 * i) * 128 + (qq) * 32]; }
#define WRITEQ(buf, sl) { char* wp = lsQ[sl] + (size_t)srow0 * 264 + scol * 8; \
    _Pragma("unroll") for (int i = 0; i < 8; ++i) { \
        uint2 ww; ww.x = pkbf(buf[i].x, buf[i].y); ww.y = pkbf(buf[i].z, buf[i].w); \
        *(uint2*)(wp + (size_t)(16 * i) * 264) = ww; } }
#define LGKMBAR { asm volatile("s_waitcnt lgkmcnt(0)" ::: "memory"); \
                  __builtin_amdgcn_s_barrier(); asm volatile("" ::: "memory"); }
#define MFMA(a, bb, c) __builtin_amdgcn_mfma_f32_32x32x16_bf16(a, bb, c, 0, 0, 0)

    // ---- B addressing: slot(chunk c) = c*1024 + w*128 + lane (+64 for odd nt) ----
    const uint4* Bq4 = (const uint4*)Wp_;
    const int vB = w * 128 + lane;

    f32x16 acc[8];   // [rg*2 + nt]
#pragma unroll
    for (int t = 0; t < 8; ++t)
        acc[t] = (f32x16){0.f,0.f,0.f,0.f, 0.f,0.f,0.f,0.f, 0.f,0.f,0.f,0.f, 0.f,0.f,0.f,0.f};

    uint4 rb[4][2];

#define STEP(f, sl) { \
        union { uint4 u; short8 s8; } b0{rb[(f) & 3][0]}, b1{rb[(f) & 3][1]}; \
        if ((f) + 4 < 32) { \
            rb[(f) & 3][0] = Bq4[(size_t)((f) + 4) * 1024 + vB]; \
            rb[(f) & 3][1] = Bq4[(size_t)((f) + 4) * 1024 + vB + 64]; \
        } \
        const char* ab = lsQ[sl] + (size_t)col * 264 + h * 16 + ((f) & 7) * 32; \
        short8 a0 = *(const short8*)(ab); \
        short8 a1 = *(const short8*)(ab + 32 * 264); \
        short8 a2 = *(const short8*)(ab + 64 * 264); \
        short8 a3 = *(const short8*)(ab + 96 * 264); \
        acc[0] = MFMA(a0, b0.s8, acc[0]); \
        acc[1] = MFMA(a0, b1.s8, acc[1]); \
        acc[2] = MFMA(a1, b0.s8, acc[2]); \
        acc[3] = MFMA(a1, b1.s8, acc[3]); \
        acc[4] = MFMA(a2, b0.s8, acc[4]); \
        acc[5] = MFMA(a2, b1.s8, acc[5]); \
        acc[6] = MFMA(a3, b0.s8, acc[6]); \
        acc[7] = MFMA(a3, b1.s8, acc[7]); }

#define QUARTER(f0, sl) { STEP((f0)+0, sl) STEP((f0)+1, sl) STEP((f0)+2, sl) STEP((f0)+3, sl) \
                          STEP((f0)+4, sl) STEP((f0)+5, sl) STEP((f0)+6, sl) STEP((f0)+7, sl) }

#define RB_LOAD4 { _Pragma("unroll") for (int f = 0; f < 4; ++f) { \
        rb[f][0] = Bq4[(size_t)f * 1024 + vB]; \
        rb[f][1] = Bq4[(size_t)f * 1024 + vB + 64]; } }

#define ZERO_ACC { _Pragma("unroll") for (int t = 0; t < 8; ++t) \
        acc[t] = (f32x16){0.f,0.f,0.f,0.f, 0.f,0.f,0.f,0.f, 0.f,0.f,0.f,0.f, 0.f,0.f,0.f,0.f}; }

    // ---- TAIL: epilogue + softmax + rescale + ctx for one tile ----
#define TAIL(r0t, b_t, dix) { \
    { const int d0 = w * 64 + col; \
      const float wv0 = Wv_[d0], wv1 = Wv_[d0 + 32]; \
      const float bs0 = bias_[(b_t) * DEC + d0], bs1 = bias_[(b_t) * DEC + d0 + 32]; \
      _Pragma("unroll") for (int rg = 0; rg < 4; ++rg) { \
        _Pragma("unroll") for (int r = 0; r < 16; ++r) { \
          float val = fmaf(wv0, fast_tanh(acc[rg * 2 + 0][r] + bs0), \
                           wv1 * fast_tanh(acc[rg * 2 + 1][r] + bs1)); \
          val += __shfl_xor(val, 16); val += __shfl_xor(val, 8); \
          val += __shfl_xor(val, 4);  val += __shfl_xor(val, 2); \
          val += __shfl_xor(val, 1); \
          if (col == r) red[w][rg * 32 + ((r & 3) + 8 * (r >> 2) + 4 * h)] = val; \
        } } } \
    __syncthreads(); \
    { float ev = 0.f, svv = 0.f; \
      if (tid < 128) { \
        svv = red[0][tid] + red[1][tid] + red[2][tid] + red[3][tid] \
            + red[4][tid] + red[5][tid] + red[6][tid] + red[7][tid]; \
        if (word_mask[(r0t) + tid] == 0) svv = -INFINITY; \
        float mx = svv; \
        _Pragma("unroll") for (int o = 1; o <= 32; o <<= 1) mx = fmaxf(mx, __shfl_xor(mx, o)); \
        if (lane == 0) rmax2[tid >> 6] = mx; \
      } \
      __syncthreads(); \
      if (tid < 128) { \
        float mx = fmaxf(rmax2[0], rmax2[1]); \
        ev = __expf(svv - mx); \
        float sum = ev; \
        _Pragma("unroll") for (int o = 1; o <= 32; o <<= 1) sum += __shfl_xor(sum, o); \
        if (lane == 0) rsum2[tid >> 6] = sum; \
      } \
      __syncthreads(); \
      if (tid < 128) { \
        float sum = rsum2[0] + rsum2[1]; \
        float resc = s_dattn2[dix] * (ev / sum); \
        sS[tid] = resc; \
        rescaled_out[(r0t) + tid] = resc; \
      } \
      __syncthreads(); \
    } \
    { const int hh = tid >> 7; \
      const int m4 = tid & 127; \
      const float4* Xr = (const float4*)X + (size_t)(r0t) * 128 + (size_t)hh * 32 * 128 + m4; \
      float4 a = {0.f, 0.f, 0.f, 0.f}; \
      _Pragma("unroll 8") for (int i = 0; i < 32; ++i) { \
        float rr = sS[hh * 32 + i]; \
        float4 v = Xr[(size_t)i * 128]; \
        a.x = fmaf(rr, v.x, a.x); a.y = fmaf(rr, v.y, a.y); \
        a.z = fmaf(rr, v.z, a.z); a.w = fmaf(rr, v.w, a.w); \
      } \
      if (hh) part[(hh - 1) * 128 + m4] = a; \
      __syncthreads(); \
      if (hh == 0) { \
        float4 p0 = part[m4], p1 = part[128 + m4], p2 = part[256 + m4]; \
        a.x += p0.x + p1.x + p2.x; a.y += p0.y + p1.y + p2.y; \
        a.z += p0.z + p1.z + p2.z; a.w += p0.w + p1.w + p2.w; \
        float* dst = ctx_out + (size_t)(b_t) * MEM + m4 * 4; \
        atomicAdd(dst + 0, a.x); atomicAdd(dst + 1, a.y); \
        atomicAdd(dst + 2, a.z); atomicAdd(dst + 3, a.w); \
      } } }

    float4 sb0[8], sb1[8];

    // ---- P0: prologue ----
    ISSUEQ(sb0, 0, Xb1);
    ISSUEQ(sb1, 1, Xb1);
    // doc softmax for BOTH tiles (waves 0,1; lanes 0..31), overlaps load latency
    if (w < 2 && lane < 32) {
        const int bqv = bid + w * 256;
        const int bv = bqv >> 5;
        const int di = bv * 32 + lane;
        float dsv = doc_scores[di];
        if (doc_mask[di] == 0) dsv = -INFINITY;
        float mx = dsv;
#pragma unroll
        for (int o = 1; o <= 16; o <<= 1) mx = fmaxf(mx, __shfl_xor(mx, o));
        float e = __expf(dsv - mx);
        float sum = e;
#pragma unroll
        for (int o = 1; o <= 16; o <<= 1) sum += __shfl_xor(sum, o);
        if (lane == (bqv & 31)) s_dattn2[w] = e / sum;
    }
    WRITEQ(sb0, 0);
    RB_LOAD4;
    LGKMBAR;

    // ---- P1 ----
    ISSUEQ(sb0, 2, Xb1);
    QUARTER(0, 0);
    WRITEQ(sb1, 1);
    LGKMBAR;

    // ---- P2 ----
    ISSUEQ(sb1, 3, Xb1);
    QUARTER(8, 1);
    WRITEQ(sb0, 2);
    LGKMBAR;

    // ---- P3: start staging tile 2 ----
    ISSUEQ(sb0, 0, Xb2);
    QUARTER(16, 2);
    WRITEQ(sb1, 3);
    LGKMBAR;

    // ---- P4 ----
    ISSUEQ(sb1, 1, Xb2);
    QUARTER(24, 3);
    WRITEQ(sb0, 0);
    RB_LOAD4;          // ring restart for tile 2 (L2-hot)
    LGKMBAR;

    // ---- P5: tile-1 tail; tile-2 staging continues around it ----
    WRITEQ(sb1, 1);
    ISSUEQ(sb0, 2, Xb2);
    TAIL(r01, b1, 0);
    ZERO_ACC;
    ISSUEQ(sb1, 3, Xb2);
    LGKMBAR;

    // ---- P6 ----
    QUARTER(0, 0);
    WRITEQ(sb0, 2);
    LGKMBAR;

    // ---- P7 ----
    QUARTER(8, 1);
    WRITEQ(sb1, 3);
    LGKMBAR;

    // ---- P8/P9 ----
    QUARTER(16, 2);
    QUARTER(24, 3);
    TAIL(r02, b2, 1);
}

extern "C" void kernel_launch(void* const* d_in, const int* in_sizes, int n_in,
                              void* d_out, int out_size, void* d_ws, size_t ws_size,
                              hipStream_t stream) {
    const float* decoder_state = (const float*)d_in[0];
    const float* doc_memory    = (const float*)d_in[1];
    const float* word_memory   = (const float*)d_in[2];
    const float* topic_dist    = (const float*)d_in[3];
    const int*   doc_mask      = (const int*)d_in[4];
    const int*   word_mask     = (const int*)d_in[5];
    const float* Wv  = (const float*)d_in[6];
    const float* Wd  = (const float*)d_in[7];
    const float* Wt  = (const float*)d_in[8];
    const float* Wm  = (const float*)d_in[9];
    const float* Wv2 = (const float*)d_in[10];
    const float* Wd2 = (const float*)d_in[11];
    const float* Wt2 = (const float*)d_in[12];
    const float* Wm2 = (const float*)d_in[13];

    float* ws = (float*)d_ws;
    unsigned short* Wp  = (unsigned short*)(ws + WS_WP);
    float* bias1       = ws + WS_BIAS1;
    float* bias2       = ws + WS_BIAS2;
    float* doc_scores  = ws + WS_DOCSC;

    float* ctx_out      = (float*)d_out;                 // [16][512]
    float* rescaled_out = (float*)d_out + BATCH * MEM;   // [16][32][128]

    setup_kernel<<<128 + 4096 + 4, 256, 0, stream>>>(Wm, Wp,
                                                     decoder_state, topic_dist,
                                                     Wd, Wt, Wd2, Wt2, bias1, bias2, ctx_out);
    doc_score_kernel<<<256, 512, 0, stream>>>(doc_memory, Wm2, Wv2, bias2, doc_scores);
    word_fused_kernel<<<256, 512, 0, stream>>>(word_memory, Wp, Wv, bias1,
                                               doc_scores, doc_mask, word_mask,
                                               rescaled_out, ctx_out);
}

// Round 7
// 312.367 us; speedup vs baseline: 1.3740x; 1.1616x over previous
//
#include <hip/hip_runtime.h>
#include <hip/hip_bf16.h>
#include <math.h>

// Problem constants
#define BATCH 16
#define L1 32
#define L2 128
#define DEC 512
#define MEM 512
#define TOPN 50
#define NROWS (BATCH * L1 * L2)   // 65536 word rows
#define NBQ (BATCH * L1)          // 512 (b,q) rows

typedef short short8 __attribute__((ext_vector_type(8)));
typedef float f32x16 __attribute__((ext_vector_type(16)));

// ---------------- ws layout (floats) ----------------
#define WS_WP     0          // perm bf16 Wm : 32768 slots x 16B = floats [0,131072)
#define WS_BIAS1  262144
#define WS_BIAS2  270336
#define WS_DOCSC  278528     // doc scores [512]

// packed pair via v_cvt_pk_bf16_f32
__device__ __forceinline__ unsigned int pkbf(float a, float b) {
    __hip_bfloat162 h = __float22bfloat162_rn(float2{a, b});
    union { __hip_bfloat162 h; unsigned int u; } c{h};
    return c.u;
}

__device__ __forceinline__ float fast_tanh(float x) {
    return 1.f - 2.f / (__expf(2.f * x) + 1.f);
}

__device__ __forceinline__ float wave_sum64(float v) {
    v += __shfl_xor(v, 1);
    v += __shfl_xor(v, 2);
    v += __shfl_xor(v, 4);
    v += __shfl_xor(v, 8);
    v += __shfl_xor(v, 16);
    v += __shfl_xor(v, 32);
    return v;
}

// ============ kernel 0 (setup): permute Wm + bias via wave-per-output + zero ctx ============
// permute slot s (16B) holds Wm[d][k..k+7] bf16: s = C*1024 + nt*64 + k8*32 + n
//   d = nt*32+n ; k = C*16 + k8*8      (layout HW-verified)
__global__ __launch_bounds__(256) void setup_kernel(
    const float* __restrict__ Wm,
    unsigned short* __restrict__ Wp,
    const float* __restrict__ dec, const float* __restrict__ topic,
    const float* __restrict__ Wd, const float* __restrict__ Wt,
    const float* __restrict__ Wd2, const float* __restrict__ Wt2,
    float* __restrict__ bias1, float* __restrict__ bias2,
    float* __restrict__ ctx_out)
{
    const int bid = blockIdx.x;
    const int tid = threadIdx.x;
    if (bid < 128) {
        int s = bid * 256 + tid;                    // 0..32767
        int C = s >> 10;
        int u = s & 1023;
        int nt = u >> 6, k8 = (u >> 5) & 1, n_in = u & 31;
        int d = nt * 32 + n_in;
        int k = C * 16 + k8 * 8;

        const float4* src = (const float4*)(Wm + (size_t)d * DEC + k);
        float4 v0 = src[0], v1 = src[1];
        uint4 v;
        v.x = pkbf(v0.x, v0.y); v.y = pkbf(v0.z, v0.w);
        v.z = pkbf(v1.x, v1.y); v.w = pkbf(v1.z, v1.w);
        ((uint4*)Wp)[s] = v;
    } else if (bid < 128 + 4096) {
        // one bias output per wave: gw in [0,16384)
        int gw = (bid - 128) * 4 + (tid >> 6);
        int lane = tid & 63;
        int mat = gw >> 13;                 // 0: bias1 (Wd,Wt), 1: bias2 (Wd2,Wt2)
        int rem = gw & 8191;
        int bb = rem >> 9;                  // 0..15
        int d = rem & 511;                  // 0..511

        const float* wrow = (mat ? Wd2 : Wd) + (size_t)d * DEC;
        const float* drow = dec + (size_t)bb * DEC;
        float4 a0 = ((const float4*)wrow)[lane * 2];
        float4 a1 = ((const float4*)wrow)[lane * 2 + 1];
        float4 x0 = ((const float4*)drow)[lane * 2];
        float4 x1 = ((const float4*)drow)[lane * 2 + 1];
        float acc = a0.x * x0.x;
        acc = fmaf(a0.y, x0.y, acc);
        acc = fmaf(a0.z, x0.z, acc);
        acc = fmaf(a0.w, x0.w, acc);
        acc = fmaf(a1.x, x1.x, acc);
        acc = fmaf(a1.y, x1.y, acc);
        acc = fmaf(a1.z, x1.z, acc);
        acc = fmaf(a1.w, x1.w, acc);
        const float* trow = (mat ? Wt2 : Wt) + (size_t)d * TOPN;
        if (lane < TOPN) acc = fmaf(trow[lane], topic[bb * TOPN + lane], acc);
#pragma unroll
        for (int o = 1; o <= 32; o <<= 1) acc += __shfl_xor(acc, o);
        if (lane == 0) (mat ? bias2 : bias1)[bb * DEC + d] = acc;
    } else {
        // zero ctx accumulator region of d_out (8192 floats), 4 blocks
        int i = (bid - (128 + 4096)) * 256 + tid;   // 0..1023
        float4 z = {0.f, 0.f, 0.f, 0.f};
        ((float4*)ctx_out)[i * 2] = z;
        ((float4*)ctx_out)[i * 2 + 1] = z;
    }
}

// ============ doc score kernel: wide fp32 VALU (256 blocks, 512 thr) ============
// Block = 2 doc rows (same batch). Replaces the 4-8-block MFMA doc dispatch
// (which took ~117 us on 4 CUs in R7's counters). Wm2 is L2-resident (1 MB/XCD).
__global__ __launch_bounds__(512) void doc_score_kernel(
    const float* __restrict__ Xd,     // doc_memory [512][512]
    const float* __restrict__ Wm2,    // [512][512] row-major [d][m]
    const float* __restrict__ Wv2,    // [512]
    const float* __restrict__ bias2,  // [16][512]
    float* __restrict__ doc_scores)   // [512]
{
    __shared__ float wsum[2][8];
    const int tid = threadIdx.x;
    const int lane = tid & 63;
    const int w = tid >> 6;            // 0..7
    const int row0 = blockIdx.x * 2;   // even -> both rows same batch
    const int b = row0 >> 5;

    const float4* X0 = (const float4*)(Xd + (size_t)row0 * MEM) + lane * 2;
    const float4* X1 = (const float4*)(Xd + (size_t)(row0 + 1) * MEM) + lane * 2;
    float4 xa0 = X0[0], xb0 = X0[1];
    float4 xa1 = X1[0], xb1 = X1[1];

    float s0 = 0.f, s1 = 0.f;
#pragma unroll 2
    for (int dd = 0; dd < 64; dd += 2) {
        const int d = w * 64 + dd;
        const float4* W0 = (const float4*)(Wm2 + (size_t)d * MEM) + lane * 2;
        const float4* W1 = (const float4*)(Wm2 + (size_t)(d + 1) * MEM) + lane * 2;
        float4 wa0 = W0[0], wb0 = W0[1];
        float4 wa1 = W1[0], wb1 = W1[1];

        float p00 = wa0.x * xa0.x, p01 = wa1.x * xa0.x;
        float p10 = wa0.x * xa1.x, p11 = wa1.x * xa1.x;
        p00 = fmaf(wa0.y, xa0.y, p00); p01 = fmaf(wa1.y, xa0.y, p01);
        p10 = fmaf(wa0.y, xa1.y, p10); p11 = fmaf(wa1.y, xa1.y, p11);
        p00 = fmaf(wa0.z, xa0.z, p00); p01 = fmaf(wa1.z, xa0.z, p01);
        p10 = fmaf(wa0.z, xa1.z, p10); p11 = fmaf(wa1.z, xa1.z, p11);
        p00 = fmaf(wa0.w, xa0.w, p00); p01 = fmaf(wa1.w, xa0.w, p01);
        p10 = fmaf(wa0.w, xa1.w, p10); p11 = fmaf(wa1.w, xa1.w, p11);
        p00 = fmaf(wb0.x, xb0.x, p00); p01 = fmaf(wb1.x, xb0.x, p01);
        p10 = fmaf(wb0.x, xb1.x, p10); p11 = fmaf(wb1.x, xb1.x, p11);
        p00 = fmaf(wb0.y, xb0.y, p00); p01 = fmaf(wb1.y, xb0.y, p01);
        p10 = fmaf(wb0.y, xb1.y, p10); p11 = fmaf(wb1.y, xb1.y, p11);
        p00 = fmaf(wb0.z, xb0.z, p00); p01 = fmaf(wb1.z, xb0.z, p01);
        p10 = fmaf(wb0.z, xb1.z, p10); p11 = fmaf(wb1.z, xb1.z, p11);
        p00 = fmaf(wb0.w, xb0.w, p00); p01 = fmaf(wb1.w, xb0.w, p01);
        p10 = fmaf(wb0.w, xb1.w, p10); p11 = fmaf(wb1.w, xb1.w, p11);

        p00 = wave_sum64(p00);
        p01 = wave_sum64(p01);
        p10 = wave_sum64(p10);
        p11 = wave_sum64(p11);
        if (lane == 0) {
            float wva = Wv2[d], wvb = Wv2[d + 1];
            float bsa = bias2[b * DEC + d], bsb = bias2[b * DEC + d + 1];
            s0 += fmaf(wva, fast_tanh(p00 + bsa), wvb * fast_tanh(p01 + bsb));
            s1 += fmaf(wva, fast_tanh(p10 + bsa), wvb * fast_tanh(p11 + bsb));
        }
    }
    if (lane == 0) { wsum[0][w] = s0; wsum[1][w] = s1; }
    __syncthreads();
    if (tid < 2) {
        float s = 0.f;
#pragma unroll
        for (int i = 0; i < 8; ++i) s += wsum[tid][i];
        doc_scores[row0 + tid] = s;
    }
}

// ============ fused word kernel (R0-verified, 107 us): doc-softmax + MFMA scores
//              + softmax + rescale + ctx. Byte-identical to the session-best config:
//              VGPR 92 + 128 AGPR, no spill; A 4-deep / B 2-deep prefetch. ============
__global__ __launch_bounds__(512) void fused_word_kernel(
    const float* __restrict__ X,            // word_memory [65536][512]
    const unsigned short* __restrict__ Wp,  // permuted bf16 Wm
    const float* __restrict__ Wv,           // [512]
    const float* __restrict__ bias1,        // [16][512]
    const float* __restrict__ doc_scores,   // [512]
    const int* __restrict__ doc_mask,       // [512]
    const int* __restrict__ word_mask,      // [65536]
    float* __restrict__ rescaled_out,       // d_out + 8192
    float* __restrict__ ctx_out)            // d_out [16][512], pre-zeroed, atomic
{
    __shared__ __align__(16) short lsA[2 * 2048];   // 2 x 4KB double buffer
    __shared__ float red[8][128];
    __shared__ float sS[128];
    __shared__ float rmax2[2], rsum2[2];
    __shared__ float s_dattn;
    __shared__ __align__(16) float4 part[3 * 128];

    const int tid = threadIdx.x;
    const int lane = tid & 63;
    const int wid = tid >> 6;          // 0..7
    const int bq = blockIdx.x;         // 0..511
    const int r0 = bq * L2;            // first word row
    const int b = bq >> 5;
    const int q = bq & 31;

    // ---- doc softmax for this block's (b,q): one scalar ----
    if (tid < 32) {
        int di = b * 32 + tid;
        float dsv = doc_scores[di];
        if (doc_mask[di] == 0) dsv = -INFINITY;
        float mx = dsv;
#pragma unroll
        for (int o = 1; o <= 16; o <<= 1) mx = fmaxf(mx, __shfl_xor(mx, o));
        float e = __expf(dsv - mx);
        float sum = e;
#pragma unroll
        for (int o = 1; o <= 16; o <<= 1) sum += __shfl_xor(sum, o);
        if (tid == q) s_dattn = e / sum;
    }

    // ---- A staging map: thread -> (row, kq) ----
    const int row = tid >> 2;          // 0..127
    const int kq = tid & 3;            // float4 index within 16-k chunk
    const int mt_s = row >> 5;
    const int rl_s = row & 31;
    const int k8_s = kq >> 1;
    const int q4 = (kq & 1) * 4;       // short offset within slot
    const int slot_s = mt_s * 64 + k8_s * 32 + rl_s;
    const float4* xs = (const float4*)(X + (size_t)(r0 + row) * DEC) + kq;

    const uint4* Bp = (const uint4*)Wp;
    const int boff = wid * 128 + lane;

    f32x16 acc[8];   // [mt*2 + nt]
#pragma unroll
    for (int t = 0; t < 8; ++t)
        acc[t] = (f32x16){0.f,0.f,0.f,0.f, 0.f,0.f,0.f,0.f, 0.f,0.f,0.f,0.f, 0.f,0.f,0.f,0.f};

    const short8* lA = (const short8*)lsA;

    // ---- deep prefetch: A chunks 0..3, B chunks 0..1 ----
    float4 va[4];
#pragma unroll
    for (int i = 0; i < 4; ++i) va[i] = xs[i * 4];
    uint4 ub0[2], ub1[2];
#pragma unroll
    for (int i = 0; i < 2; ++i) {
        ub0[i] = Bp[i * 1024 + boff];
        ub1[i] = Bp[i * 1024 + boff + 64];
    }

#pragma unroll
    for (int c = 0; c < 32; ++c) {
        const int p = c & 1;
        const int ia = c & 3;
        // write A chunk c into buffer p (waits vmcnt for va[ia], issued 4 iters ago)
        uint2 w2;
        w2.x = pkbf(va[ia].x, va[ia].y);
        w2.y = pkbf(va[ia].z, va[ia].w);
        *(uint2*)&lsA[(p * 256 + slot_s) * 8 + q4] = w2;
        __syncthreads();

        // refill prefetch: A 4 ahead, B 2 ahead (wrap -> dead-but-valid loads)
        va[ia] = xs[((c + 4) & 31) * 4];
        uint4 nb0 = Bp[((c + 2) & 31) * 1024 + boff];
        uint4 nb1 = Bp[((c + 2) & 31) * 1024 + boff + 64];

        short8 a0 = lA[p * 256 + 0 * 64 + lane];
        short8 a1 = lA[p * 256 + 1 * 64 + lane];
        short8 a2 = lA[p * 256 + 2 * 64 + lane];
        short8 a3 = lA[p * 256 + 3 * 64 + lane];
        union { uint4 u; short8 s; } cb0{ub0[p]}, cb1{ub1[p]};
        acc[0] = __builtin_amdgcn_mfma_f32_32x32x16_bf16(a0, cb0.s, acc[0], 0, 0, 0);
        acc[1] = __builtin_amdgcn_mfma_f32_32x32x16_bf16(a0, cb1.s, acc[1], 0, 0, 0);
        acc[2] = __builtin_amdgcn_mfma_f32_32x32x16_bf16(a1, cb0.s, acc[2], 0, 0, 0);
        acc[3] = __builtin_amdgcn_mfma_f32_32x32x16_bf16(a1, cb1.s, acc[3], 0, 0, 0);
        acc[4] = __builtin_amdgcn_mfma_f32_32x32x16_bf16(a2, cb0.s, acc[4], 0, 0, 0);
        acc[5] = __builtin_amdgcn_mfma_f32_32x32x16_bf16(a2, cb1.s, acc[5], 0, 0, 0);
        acc[6] = __builtin_amdgcn_mfma_f32_32x32x16_bf16(a3, cb0.s, acc[6], 0, 0, 0);
        acc[7] = __builtin_amdgcn_mfma_f32_32x32x16_bf16(a3, cb1.s, acc[7], 0, 0, 0);

        ub0[p] = nb0; ub1[p] = nb1;
    }

    // ---- epilogue: tanh + Wv partial over this wave's 64 d ----
    // C/D layout (32x32, HW-verified): col = lane&31, row_in = (r&3) + 8*(r>>2) + 4*(lane>>5)
    const int col = lane & 31;
    const int h = lane >> 5;
    float wv0, wv1, bs0, bs1;
    {
        int d0 = wid * 64 + col;
        int d1 = wid * 64 + 32 + col;
        wv0 = Wv[d0]; wv1 = Wv[d1];
        bs0 = bias1[b * DEC + d0]; bs1 = bias1[b * DEC + d1];
    }
#pragma unroll
    for (int mt = 0; mt < 4; ++mt) {
#pragma unroll
        for (int r = 0; r < 16; ++r) {
            float p = fmaf(wv0, fast_tanh(acc[mt * 2 + 0][r] + bs0),
                           wv1 * fast_tanh(acc[mt * 2 + 1][r] + bs1));
            p += __shfl_xor(p, 16);
            p += __shfl_xor(p, 8);
            p += __shfl_xor(p, 4);
            p += __shfl_xor(p, 2);
            p += __shfl_xor(p, 1);
            if (col == r) {
                int row_in = (r & 3) + 8 * (r >> 2) + 4 * h;
                red[wid][mt * 32 + row_in] = p;
            }
        }
    }
    __syncthreads();

    // ---- block softmax over 128 words (threads 0..127) ----
    float e = 0.f, sv = 0.f;
    if (tid < 128) {
        sv = red[0][tid] + red[1][tid] + red[2][tid] + red[3][tid]
           + red[4][tid] + red[5][tid] + red[6][tid] + red[7][tid];
        if (word_mask[r0 + tid] == 0) sv = -INFINITY;
        float mx = sv;
#pragma unroll
        for (int o = 1; o <= 32; o <<= 1) mx = fmaxf(mx, __shfl_xor(mx, o));
        if (lane == 0) rmax2[wid] = mx;
    }
    __syncthreads();
    if (tid < 128) {
        float mx = fmaxf(rmax2[0], rmax2[1]);
        e = __expf(sv - mx);
        float sum = e;
#pragma unroll
        for (int o = 1; o <= 32; o <<= 1) sum += __shfl_xor(sum, o);
        if (lane == 0) rsum2[wid] = sum;
    }
    __syncthreads();
    if (tid < 128) {
        float sum = rsum2[0] + rsum2[1];
        float resc = s_dattn * (e / sum);
        sS[tid] = resc;
        rescaled_out[r0 + tid] = resc;
    }
    __syncthreads();

    // ---- context partial (fp32 X re-read, L2-hot) + atomic accumulate ----
    const int hh = tid >> 7;          // 0..3: w-group of 32
    const int m4 = tid & 127;         // float4 index in m
    const float4* Xr = (const float4*)X + (size_t)r0 * 128 + (size_t)hh * 32 * 128 + m4;
    float4 a = {0.f, 0.f, 0.f, 0.f};
#pragma unroll 8
    for (int i = 0; i < 32; ++i) {
        float rr = sS[hh * 32 + i];
        float4 v = Xr[(size_t)i * 128];
        a.x = fmaf(rr, v.x, a.x);
        a.y = fmaf(rr, v.y, a.y);
        a.z = fmaf(rr, v.z, a.z);
        a.w = fmaf(rr, v.w, a.w);
    }
    if (hh) part[(hh - 1) * 128 + m4] = a;
    __syncthreads();
    if (hh == 0) {
        float4 p0 = part[m4], p1 = part[128 + m4], p2 = part[256 + m4];
        a.x += p0.x + p1.x + p2.x;
        a.y += p0.y + p1.y + p2.y;
        a.z += p0.z + p1.z + p2.z;
        a.w += p0.w + p1.w + p2.w;
        float* dst = ctx_out + (size_t)b * MEM + m4 * 4;
        atomicAdd(dst + 0, a.x);
        atomicAdd(dst + 1, a.y);
        atomicAdd(dst + 2, a.z);
        atomicAdd(dst + 3, a.w);
    }
}

extern "C" void kernel_launch(void* const* d_in, const int* in_sizes, int n_in,
                              void* d_out, int out_size, void* d_ws, size_t ws_size,
                              hipStream_t stream) {
    const float* decoder_state = (const float*)d_in[0];
    const float* doc_memory    = (const float*)d_in[1];
    const float* word_memory   = (const float*)d_in[2];
    const float* topic_dist    = (const float*)d_in[3];
    const int*   doc_mask      = (const int*)d_in[4];
    const int*   word_mask     = (const int*)d_in[5];
    const float* Wv  = (const float*)d_in[6];
    const float* Wd  = (const float*)d_in[7];
    const float* Wt  = (const float*)d_in[8];
    const float* Wm  = (const float*)d_in[9];
    const float* Wv2 = (const float*)d_in[10];
    const float* Wd2 = (const float*)d_in[11];
    const float* Wt2 = (const float*)d_in[12];
    const float* Wm2 = (const float*)d_in[13];

    float* ws = (float*)d_ws;
    unsigned short* Wp  = (unsigned short*)(ws + WS_WP);
    float* bias1       = ws + WS_BIAS1;
    float* bias2       = ws + WS_BIAS2;
    float* doc_scores  = ws + WS_DOCSC;

    float* ctx_out      = (float*)d_out;                 // [16][512]
    float* rescaled_out = (float*)d_out + BATCH * MEM;   // [16][32][128]

    setup_kernel<<<128 + 4096 + 4, 256, 0, stream>>>(Wm, Wp,
                                                     decoder_state, topic_dist,
                                                     Wd, Wt, Wd2, Wt2, bias1, bias2, ctx_out);
    doc_score_kernel<<<256, 512, 0, stream>>>(doc_memory, Wm2, Wv2, bias2, doc_scores);
    fused_word_kernel<<<NBQ, 512, 0, stream>>>(word_memory, Wp, Wv, bias1,
                                               doc_scores, doc_mask, word_mask,
                                               rescaled_out, ctx_out);
}